// Round 10
// baseline (345.563 us; speedup 1.0000x reference)
//
#include <hip/hip_runtime.h>
#include <hip/hip_bf16.h>
#include <stdint.h>

// RSNN: T=256 steps, B=32, N_IN=256, N=2048.
// out = [3, T, B, N] fp32: zs | vs | z2s  (TBN elements each)
//
// Pipeline (all on `stream`, stream-ordered):
//   1. wt_convert: W_bern fp32 [k][n] -> Wt bf16 [n][k]   (ws +0, 8 MB)
//   2. in_gemm:    I = x @ W_in + b  (fp32) -- NO-LDS streaming design:
//                  B read straight from global (L2-resident panel), A via
//                  lane-uniform vector loads (L1 broadcast). Pure vmcnt
//                  domain, in-order, compiler-scheduled -- avoids the LDS
//                  pipe bound (R4), the SMEM/DS lgkm conflation (R6), and
//                  the asm-pipeline race (R9).
//   3. scan:       per-neuron serial v scan; writes zs, vs (fp32) and Z bf16
//   4. bern_gemm:  Y = Z @ W_bern  -- 256^2 8-phase bf16 MFMA template
//                  (T2 XOR-swizzle + T3/T4 counted vmcnt + T5 setprio)
//   5. gather_k:   z2[t,b,j] = Y[t,b,idx[t,j]]  in place (row via LDS)

#define T_STEPS 256
#define BATCH   32
#define NIN     256
#define NN      2048
#define BN_FLAT (BATCH * NN)            // 65536
#define TBN     (T_STEPS * BATCH * NN)  // 16777216
#define MROWS   (T_STEPS * BATCH)       // 8192

typedef __attribute__((ext_vector_type(4))) float fx4;
typedef __attribute__((ext_vector_type(4))) int   ix4;

__device__ __forceinline__ void gll16(const void* g, void* l) {
  typedef __attribute__((address_space(1))) void gvoid_t;
  typedef __attribute__((address_space(3))) void lvoid_t;
  __builtin_amdgcn_global_load_lds((gvoid_t*)(g), (lvoid_t*)(l), 16, 0, 0);
}

__device__ __forceinline__ void mfma16(fx4& d, ix4 a, ix4 b) {
  asm volatile("v_mfma_f32_16x16x32_bf16 %0, %1, %2, %0" : "+v"(d) : "v"(a), "v"(b));
}

// ---------------------------------------------------------------- kernel 1
__global__ __launch_bounds__(256) void wt_convert(const float* __restrict__ W,
                                                  __hip_bfloat16* __restrict__ Wt) {
  __shared__ float tile[32][33];
  const int k0 = blockIdx.y << 5, n0 = blockIdx.x << 5;
  const int tx = threadIdx.x, ty = threadIdx.y;
#pragma unroll
  for (int i = 0; i < 32; i += 8)
    tile[ty + i][tx] = W[(size_t)(k0 + ty + i) * NN + n0 + tx];
  __syncthreads();
#pragma unroll
  for (int i = 0; i < 32; i += 8)
    Wt[(size_t)(n0 + ty + i) * NN + k0 + tx] = __float2bfloat16(tile[tx][ty + i]);
}

// ---------------------------------------------------------------- kernel 2
// fp32 GEMM: I[8192][2048] = X @ Wi + bias.  NO LDS, NO barriers, NO asm.
// Block 32 rows x 256 cols, 4 waves; wave w rows m0+8w..+7; lane cols
// n0+lane*4..+3. Per 4-k group: 8 lane-uniform A fx4 loads (one L1
// broadcast transaction each) + 4 B fx4 loads (L2-resident panel) + 128
// FMAs. All loads plain global (vmcnt, in-order) -- the compiler's own
// fine-grained waitcnt scheduling applies. FMA order over k identical to
// all passing rounds (ascending k) -> same rounding, absmax unchanged.
__global__ __launch_bounds__(256) void in_gemm(const float* __restrict__ X,
                                               const float* __restrict__ Wi,
                                               const float* __restrict__ bias,
                                               float* __restrict__ I) {
  const int tid = threadIdx.x;
  const int lane = tid & 63;
  const int m0 = blockIdx.x * 32, n0 = blockIdx.y * 256;
  const int row0 = m0 + 8 * (tid >> 6);
  const float* aP = X + (size_t)row0 * NIN;
  const float* bP = Wi + n0 + lane * 4;

  fx4 acc[8] = {};

#pragma unroll 2
  for (int k = 0; k < NIN; k += 4) {
    fx4 a[8], b[4];
#pragma unroll
    for (int r = 0; r < 8; ++r) a[r] = *(const fx4*)&aP[r * NIN + k];
#pragma unroll
    for (int kk = 0; kk < 4; ++kk) b[kk] = *(const fx4*)&bP[(size_t)(k + kk) * NN];
#pragma unroll
    for (int kk = 0; kk < 4; ++kk)
#pragma unroll
      for (int r = 0; r < 8; ++r)
#pragma unroll
        for (int c = 0; c < 4; ++c)
          acc[r][c] = fmaf(a[r][kk], b[kk][c], acc[r][c]);
  }

#pragma unroll
  for (int r = 0; r < 8; ++r) {
    fx4 res;
#pragma unroll
    for (int c = 0; c < 4; ++c) res[c] = acc[r][c] + bias[n0 + lane * 4 + c];
    *(fx4*)&I[(size_t)(row0 + r) * NN + n0 + lane * 4] = res;
  }
}

// ---------------------------------------------------------------- kernel 3
__device__ __forceinline__ void scan_body(float* zs, float* vsout,
                                          const float* I, __hip_bfloat16* Zb) {
  const int nid = blockIdx.x * 256 + threadIdx.x;  // 0..65535
  float v = 0.f;
  for (int t0 = 0; t0 < T_STEPS; t0 += 8) {
    float iin[8];
#pragma unroll
    for (int u = 0; u < 8; ++u)
      iin[u] = I[(size_t)(t0 + u) * BN_FLAT + nid];
#pragma unroll
    for (int u = 0; u < 8; ++u) {
      float nv = __fadd_rn(__fmul_rn(0.9048374180359595f, v), iin[u]);
      nv = fminf(fmaxf(nv, -1.0f), 1.01f);
      const bool sp = nv > 1.0f;
      const float z = sp ? 1.0f : 0.0f;
      nv = sp ? -1.0f : nv;
      const size_t off = (size_t)(t0 + u) * BN_FLAT + nid;
      zs[off] = z;
      vsout[off] = nv;
      Zb[off] = __float2bfloat16(z);
      v = nv;
    }
  }
}

__global__ __launch_bounds__(256) void scan_sep(float* __restrict__ out,
                                                const float* __restrict__ I,
                                                __hip_bfloat16* __restrict__ Zb) {
  scan_body(out, out + (size_t)TBN, I, Zb);
}

__global__ __launch_bounds__(256) void scan_inp(float* out, __hip_bfloat16* Zb) {
  scan_body(out, out + (size_t)TBN, out + (size_t)TBN, Zb);
}

// ---------------------------------------------------------------- kernel 4
// 256x256 8-phase bf16 MFMA GEMM: Y[8192][2048] = Z[8192][2048] @ Wt^T.
// (R5 winner, unchanged.) BK=64, 8 waves (2M x 4N), 512 thr, LDS 128 KiB.
// T2 XOR-swizzle both-sides; T3/T4 counted vmcnt(4); T5 setprio.
__global__ __launch_bounds__(512, 2) void bern_gemm(const __hip_bfloat16* __restrict__ Z,
                                                    const __hip_bfloat16* __restrict__ Wt,
                                                    float* __restrict__ Y) {
  __shared__ __align__(16) char lds[131072];
  const int tid = threadIdx.x;
  const int l = tid & 63, wid = tid >> 6;
  const int wr = wid >> 2, wc = wid & 3;       // 2 x 4 wave grid
  const int l15 = l & 15, l4 = l >> 4;
  const int swz = (l & 7) << 4;                // lane-constant row-XOR
  const int colp[2] = { (l4 * 16) ^ swz, (64 + l4 * 16) ^ swz };
  const int m0 = blockIdx.x * 256, n0 = blockIdx.y * 256;
  const int aoff = wr * 16384 + l15 * 128;                          // A: half=wr
  const int boff = 65536 + (wc >> 1) * 16384 + ((wc & 1) * 64 + l15) * 128;
  const int colsel = ((tid & 7) ^ ((tid >> 3) & 7)) * 16;
  const char* gA_ = (const char*)Z + ((size_t)(m0 + (tid >> 3)) << 12) + colsel;
  const char* gB_ = (const char*)Wt + ((size_t)(n0 + (tid >> 3)) << 12) + colsel;

  fx4 acc[8][4] = {};
  ix4 af[4][2], bf[4][2];

#define STAGE_A(tt, h)                                                       \
  do {                                                                       \
    const char* g = gA_ + ((size_t)((h) * 128) << 12) + (size_t)(tt) * 128;  \
    char* d = lds + (((tt) & 1) * 32768) + (h) * 16384 + tid * 16;           \
    gll16(g, d);                                                             \
    gll16(g + ((size_t)64 << 12), d + 8192);                                 \
  } while (0)
#define STAGE_B(tt, h)                                                       \
  do {                                                                       \
    const char* g = gB_ + ((size_t)((h) * 128) << 12) + (size_t)(tt) * 128;  \
    char* d = lds + 65536 + (((tt) & 1) * 32768) + (h) * 16384 + tid * 16;   \
    gll16(g, d);                                                             \
    gll16(g + ((size_t)64 << 12), d + 8192);                                 \
  } while (0)
#define LDA(mh)                                                              \
  _Pragma("unroll") for (int mf = 0; mf < 4; ++mf)                           \
    _Pragma("unroll") for (int ks = 0; ks < 2; ++ks)                         \
      af[mf][ks] = *(const ix4*)(lb + aoff + ((mh)*4 + mf) * 2048 + colp[ks]);
#define LDB(nh)                                                              \
  _Pragma("unroll") for (int nf = 0; nf < 2; ++nf)                           \
    _Pragma("unroll") for (int ks = 0; ks < 2; ++ks)                         \
      bf[(nh)*2 + nf][ks] = *(const ix4*)(lb + boff + ((nh)*2 + nf) * 2048 + colp[ks]);
#define MFMA_QUAD(mh, nh)                                                    \
  do {                                                                       \
    __builtin_amdgcn_s_setprio(1);                                           \
    _Pragma("unroll") for (int ks = 0; ks < 2; ++ks)                         \
      _Pragma("unroll") for (int mf = 0; mf < 4; ++mf)                       \
        _Pragma("unroll") for (int nf = 0; nf < 2; ++nf)                     \
          mfma16(acc[(mh)*4 + mf][(nh)*2 + nf], af[mf][ks], bf[(nh)*2 + nf][ks]); \
    __builtin_amdgcn_s_setprio(0);                                           \
  } while (0)
#define SBAR asm volatile("s_barrier" ::: "memory")

  STAGE_A(0, 0); STAGE_A(0, 1); STAGE_B(0, 0); STAGE_B(0, 1);
  STAGE_B(1, 0); STAGE_B(1, 1);
  asm volatile("s_waitcnt vmcnt(4)" ::: "memory");
  SBAR;

  for (int t = 0; t < 32; ++t) {
    const char* lb = lds + (t & 1) * 32768;
    LDA(0); LDB(0);
    if (t < 31) STAGE_A(t + 1, 0);
    SBAR;
    asm volatile("s_waitcnt lgkmcnt(0)" ::: "memory");
    MFMA_QUAD(0, 0);
    SBAR;
    LDB(1);
    if (t < 31) STAGE_A(t + 1, 1);
    SBAR;
    asm volatile("s_waitcnt lgkmcnt(0)" ::: "memory");
    MFMA_QUAD(0, 1);
    SBAR;
    LDA(1);
    if (t < 30) STAGE_B(t + 2, 0);
    SBAR;
    asm volatile("s_waitcnt lgkmcnt(0)" ::: "memory");
    MFMA_QUAD(1, 0);
    SBAR;
    if (t < 30) STAGE_B(t + 2, 1);
    SBAR;
    MFMA_QUAD(1, 1);
    if (t < 30) asm volatile("s_waitcnt vmcnt(4)" ::: "memory");
    else        asm volatile("s_waitcnt vmcnt(0)" ::: "memory");
    SBAR;
  }

#undef STAGE_A
#undef STAGE_B
#undef LDA
#undef LDB
#undef MFMA_QUAD
#undef SBAR

  const int crow = l4 * 4;
#pragma unroll
  for (int MF = 0; MF < 8; ++MF)
#pragma unroll
    for (int NF = 0; NF < 4; ++NF)
#pragma unroll
      for (int j = 0; j < 4; ++j) {
        const int r = m0 + wr * 128 + MF * 16 + crow + j;
        const int c = n0 + wc * 64 + NF * 16 + l15;
        Y[(size_t)r * NN + c] = acc[MF][NF][j];
      }
}

// ---------------------------------------------------------------- kernel 5
__global__ __launch_bounds__(256) void gather_k(float* __restrict__ Y,
                                                const int* __restrict__ ridx) {
  __shared__ __align__(16) float rowbuf[NN];
  const int tb = blockIdx.x;      // 0..8191
  const int t = tb >> 5;
  float* yrow = Y + (size_t)tb * NN;
  const int tid = threadIdx.x;
#pragma unroll
  for (int i = 0; i < 2; ++i) {
    int u = tid + i * 256;
    ((fx4*)rowbuf)[u] = ((const fx4*)yrow)[u];
  }
  __syncthreads();
  const int* ir = ridx + t * NN;
#pragma unroll
  for (int i = 0; i < 8; ++i) {
    int j = tid + i * 256;
    yrow[j] = rowbuf[ir[j]];
  }
}

// ---------------------------------------------------------------- launcher
extern "C" void kernel_launch(void* const* d_in, const int* in_sizes, int n_in,
                              void* d_out, int out_size, void* d_ws, size_t ws_size,
                              hipStream_t stream) {
  const float* x      = (const float*)d_in[0];
  const float* W_in   = (const float*)d_in[1];
  const float* bias   = (const float*)d_in[2];
  const float* W_bern = (const float*)d_in[3];
  const int*   ridx   = (const int*)d_in[4];
  float* out = (float*)d_out;
  char* ws = (char*)d_ws;

  __hip_bfloat16* Wt = (__hip_bfloat16*)ws;                       // 8,388,608 B
  __hip_bfloat16* Zb = (__hip_bfloat16*)(ws + (size_t)8388608);   // 33,554,432 B
  const size_t offI = 41943040;                                   // I: 67,108,864 B
  const bool sep = ws_size >= (size_t)109051904;
  float* Ibuf = sep ? (float*)(ws + offI) : (out + (size_t)TBN);

  wt_convert<<<dim3(64, 64), dim3(32, 8), 0, stream>>>(W_bern, Wt);
  in_gemm<<<dim3(256, 8), dim3(256), 0, stream>>>(x, W_in, bias, Ibuf);
  if (sep)
    scan_sep<<<dim3(256), dim3(256), 0, stream>>>(out, Ibuf, Zb);
  else
    scan_inp<<<dim3(256), dim3(256), 0, stream>>>(out, Zb);
  bern_gemm<<<dim3(32, 8), dim3(512), 0, stream>>>(Zb, Wt, out + (size_t)2 * TBN);
  gather_k<<<dim3(8192), dim3(256), 0, stream>>>(out + (size_t)2 * TBN, ridx);
}

// Round 11
// 343.746 us; speedup vs baseline: 1.0053x; 1.0053x over previous
//
#include <hip/hip_runtime.h>
#include <hip/hip_bf16.h>
#include <stdint.h>

// RSNN: T=256 steps, B=32, N_IN=256, N=2048.
// out = [3, T, B, N] fp32: zs | vs | z2s  (TBN elements each)
//
// Pipeline (all on `stream`, stream-ordered):
//   1. wt_convert: W_bern fp32 [k][n] -> Wt bf16 [n][k]   (ws +0, 8 MB)
//   2. in_scan:    FUSED I = x@W_in + b  +  v-scan.  Block (b, n-tile-64)
//                  computes the full [256 t][64 n] I-tile (lane-uniform A
//                  from L1, B via gll16; per-element k-ascending fmaf chain
//                  identical to the split version), parks it in LDS, then
//                  one wave scans the 64 columns over t, writing zs/vs/Zb.
//                  Kills the 134 MB I round-trip + the separate scan kernel.
//   3. bern_gemm:  Y = Z @ W_bern  -- 256^2 8-phase bf16 MFMA template
//                  (T2 XOR-swizzle + T3/T4 counted vmcnt + T5 setprio)
//   4. gather_k:   z2[t,b,j] = Y[t,b,idx[t,j]]  in place (row via LDS)

#define T_STEPS 256
#define BATCH   32
#define NIN     256
#define NN      2048
#define BN_FLAT (BATCH * NN)            // 65536
#define TBN     (T_STEPS * BATCH * NN)  // 16777216
#define MROWS   (T_STEPS * BATCH)       // 8192

typedef __attribute__((ext_vector_type(4))) float fx4;
typedef __attribute__((ext_vector_type(4))) int   ix4;

__device__ __forceinline__ void gll16(const void* g, void* l) {
  typedef __attribute__((address_space(1))) void gvoid_t;
  typedef __attribute__((address_space(3))) void lvoid_t;
  __builtin_amdgcn_global_load_lds((gvoid_t*)(g), (lvoid_t*)(l), 16, 0, 0);
}

__device__ __forceinline__ void mfma16(fx4& d, ix4 a, ix4 b) {
  asm volatile("v_mfma_f32_16x16x32_bf16 %0, %1, %2, %0" : "+v"(d) : "v"(a), "v"(b));
}

// ---------------------------------------------------------------- kernel 1
__global__ __launch_bounds__(256) void wt_convert(const float* __restrict__ W,
                                                  __hip_bfloat16* __restrict__ Wt) {
  __shared__ float tile[32][33];
  const int k0 = blockIdx.y << 5, n0 = blockIdx.x << 5;
  const int tx = threadIdx.x, ty = threadIdx.y;
#pragma unroll
  for (int i = 0; i < 32; i += 8)
    tile[ty + i][tx] = W[(size_t)(k0 + ty + i) * NN + n0 + tx];
  __syncthreads();
#pragma unroll
  for (int i = 0; i < 32; i += 8)
    Wt[(size_t)(n0 + ty + i) * NN + k0 + tx] = __float2bfloat16(tile[tx][ty + i]);
}

// ---------------------------------------------------------------- kernel 2
// FUSED input-GEMM + v-scan.  Grid (b=32, ntile=32), 256 threads.
// GEMM phase: thread (tg=tid>>4, ln=tid&15) owns rows t=tg*16..+15 and
// cols n0+ln*4..+3 -> acc[16] fx4 (64 VGPR, static indices). A-loads are
// uniform across the 16 ln-lanes (4 distinct addrs/wave -> L1 broadcast);
// B staged [16][64] via one gll16/thread, read as conflict-free
// ds_read_b128 (16 lanes x 256B rows). Per-element FMA chain: k ascending
// (kq outer, kk inner) -- identical rounding to the split in_gemm.
// Scan phase: acc+bias -> LDS Itile[256][64]; wave 0 (lane=col) runs the
// serial t-recurrence, writing zs/vs (fp32, 256B/step) + Zb (bf16).
// LDS 68 KB -> 2 blocks/CU; other blocks' GEMM overlaps the scan tail.
__global__ __launch_bounds__(256) void in_scan(const float* __restrict__ X,
                                               const float* __restrict__ Wi,
                                               const float* __restrict__ bias,
                                               float* __restrict__ out,
                                               __hip_bfloat16* __restrict__ Zb) {
  __shared__ __align__(16) float Itile[T_STEPS * 64];  // 64 KB
  __shared__ __align__(16) float Bs[16 * 64];          // 4 KB
  const int tid = threadIdx.x;
  const int b = blockIdx.x;
  const int n0 = blockIdx.y * 64;
  const int tg = tid >> 4;      // 0..15: rows t = tg*16 .. +15
  const int ln = tid & 15;      // cols n0 + ln*4 .. +3

  fx4 acc[16] = {};

  // B staging: thread covers k=tid>>4, n-span (tid&15)*4; LDS linear tid*16.
  const float* gB = Wi + (size_t)(tid >> 4) * NN + n0 + (tid & 15) * 4;
  char* lB = (char*)Bs + tid * 16;
  // A base for this thread's rows (t = tg*16 + i), fixed b.
  const float* aP = X + ((size_t)(tg * 16) * BATCH + b) * NIN;

  for (int k0 = 0; k0 < NIN; k0 += 16) {
    gll16(gB, lB);
    gB += (size_t)16 * NN;
    __syncthreads();  // B(k0) ready
#pragma unroll
    for (int kq = 0; kq < 4; ++kq) {
      fx4 bv[4];
#pragma unroll
      for (int kk = 0; kk < 4; ++kk)
        bv[kk] = *(const fx4*)&Bs[(kq * 4 + kk) * 64 + ln * 4];
#pragma unroll
      for (int i = 0; i < 16; ++i) {
        fx4 a = *(const fx4*)&aP[(size_t)i * (BATCH * NIN) + k0 + kq * 4];
#pragma unroll
        for (int kk = 0; kk < 4; ++kk)
#pragma unroll
          for (int c = 0; c < 4; ++c)
            acc[i][c] = fmaf(a[kk], bv[kk][c], acc[i][c]);
      }
    }
    __syncthreads();  // before next k0 overwrites Bs
  }

  // park I + bias in LDS
  fx4 bb;
#pragma unroll
  for (int c = 0; c < 4; ++c) bb[c] = bias[n0 + ln * 4 + c];
#pragma unroll
  for (int i = 0; i < 16; ++i) {
    fx4 r;
#pragma unroll
    for (int c = 0; c < 4; ++c) r[c] = acc[i][c] + bb[c];
    *(fx4*)&Itile[(size_t)(tg * 16 + i) * 64 + ln * 4] = r;
  }
  __syncthreads();

  // serial v-scan: wave 0, lane = column. Identical math to split scan.
  if (tid < 64) {
    const int col = tid;
    float v = 0.f;
    for (int t0 = 0; t0 < T_STEPS; t0 += 8) {
      float iin[8];
#pragma unroll
      for (int u = 0; u < 8; ++u)
        iin[u] = Itile[(t0 + u) * 64 + col];
#pragma unroll
      for (int u = 0; u < 8; ++u) {
        float nv = __fadd_rn(__fmul_rn(0.9048374180359595f, v), iin[u]);
        nv = fminf(fmaxf(nv, -1.0f), 1.01f);
        const bool sp = nv > 1.0f;
        const float z = sp ? 1.0f : 0.0f;
        nv = sp ? -1.0f : nv;
        const size_t off = (size_t)(t0 + u) * BN_FLAT + (size_t)b * NN + n0 + col;
        out[off] = z;                      // zs
        out[(size_t)TBN + off] = nv;       // vs
        Zb[off] = __float2bfloat16(z);
        v = nv;
      }
    }
  }
}

// ---------------------------------------------------------------- kernel 3
// 256x256 8-phase bf16 MFMA GEMM: Y[8192][2048] = Z[8192][2048] @ Wt^T.
// (R5 winner, unchanged.) BK=64, 8 waves (2M x 4N), 512 thr, LDS 128 KiB.
// T2 XOR-swizzle both-sides; T3/T4 counted vmcnt(4); T5 setprio.
__global__ __launch_bounds__(512, 2) void bern_gemm(const __hip_bfloat16* __restrict__ Z,
                                                    const __hip_bfloat16* __restrict__ Wt,
                                                    float* __restrict__ Y) {
  __shared__ __align__(16) char lds[131072];
  const int tid = threadIdx.x;
  const int l = tid & 63, wid = tid >> 6;
  const int wr = wid >> 2, wc = wid & 3;       // 2 x 4 wave grid
  const int l15 = l & 15, l4 = l >> 4;
  const int swz = (l & 7) << 4;                // lane-constant row-XOR
  const int colp[2] = { (l4 * 16) ^ swz, (64 + l4 * 16) ^ swz };
  const int m0 = blockIdx.x * 256, n0 = blockIdx.y * 256;
  const int aoff = wr * 16384 + l15 * 128;                          // A: half=wr
  const int boff = 65536 + (wc >> 1) * 16384 + ((wc & 1) * 64 + l15) * 128;
  const int colsel = ((tid & 7) ^ ((tid >> 3) & 7)) * 16;
  const char* gA_ = (const char*)Z + ((size_t)(m0 + (tid >> 3)) << 12) + colsel;
  const char* gB_ = (const char*)Wt + ((size_t)(n0 + (tid >> 3)) << 12) + colsel;

  fx4 acc[8][4] = {};
  ix4 af[4][2], bf[4][2];

#define STAGE_A(tt, h)                                                       \
  do {                                                                       \
    const char* g = gA_ + ((size_t)((h) * 128) << 12) + (size_t)(tt) * 128;  \
    char* d = lds + (((tt) & 1) * 32768) + (h) * 16384 + tid * 16;           \
    gll16(g, d);                                                             \
    gll16(g + ((size_t)64 << 12), d + 8192);                                 \
  } while (0)
#define STAGE_B(tt, h)                                                       \
  do {                                                                       \
    const char* g = gB_ + ((size_t)((h) * 128) << 12) + (size_t)(tt) * 128;  \
    char* d = lds + 65536 + (((tt) & 1) * 32768) + (h) * 16384 + tid * 16;   \
    gll16(g, d);                                                             \
    gll16(g + ((size_t)64 << 12), d + 8192);                                 \
  } while (0)
#define LDA(mh)                                                              \
  _Pragma("unroll") for (int mf = 0; mf < 4; ++mf)                           \
    _Pragma("unroll") for (int ks = 0; ks < 2; ++ks)                         \
      af[mf][ks] = *(const ix4*)(lb + aoff + ((mh)*4 + mf) * 2048 + colp[ks]);
#define LDB(nh)                                                              \
  _Pragma("unroll") for (int nf = 0; nf < 2; ++nf)                           \
    _Pragma("unroll") for (int ks = 0; ks < 2; ++ks)                         \
      bf[(nh)*2 + nf][ks] = *(const ix4*)(lb + boff + ((nh)*2 + nf) * 2048 + colp[ks]);
#define MFMA_QUAD(mh, nh)                                                    \
  do {                                                                       \
    __builtin_amdgcn_s_setprio(1);                                           \
    _Pragma("unroll") for (int ks = 0; ks < 2; ++ks)                         \
      _Pragma("unroll") for (int mf = 0; mf < 4; ++mf)                       \
        _Pragma("unroll") for (int nf = 0; nf < 2; ++nf)                     \
          mfma16(acc[(mh)*4 + mf][(nh)*2 + nf], af[mf][ks], bf[(nh)*2 + nf][ks]); \
    __builtin_amdgcn_s_setprio(0);                                           \
  } while (0)
#define SBAR asm volatile("s_barrier" ::: "memory")

  STAGE_A(0, 0); STAGE_A(0, 1); STAGE_B(0, 0); STAGE_B(0, 1);
  STAGE_B(1, 0); STAGE_B(1, 1);
  asm volatile("s_waitcnt vmcnt(4)" ::: "memory");
  SBAR;

  for (int t = 0; t < 32; ++t) {
    const char* lb = lds + (t & 1) * 32768;
    LDA(0); LDB(0);
    if (t < 31) STAGE_A(t + 1, 0);
    SBAR;
    asm volatile("s_waitcnt lgkmcnt(0)" ::: "memory");
    MFMA_QUAD(0, 0);
    SBAR;
    LDB(1);
    if (t < 31) STAGE_A(t + 1, 1);
    SBAR;
    asm volatile("s_waitcnt lgkmcnt(0)" ::: "memory");
    MFMA_QUAD(0, 1);
    SBAR;
    LDA(1);
    if (t < 30) STAGE_B(t + 2, 0);
    SBAR;
    asm volatile("s_waitcnt lgkmcnt(0)" ::: "memory");
    MFMA_QUAD(1, 0);
    SBAR;
    if (t < 30) STAGE_B(t + 2, 1);
    SBAR;
    MFMA_QUAD(1, 1);
    if (t < 30) asm volatile("s_waitcnt vmcnt(4)" ::: "memory");
    else        asm volatile("s_waitcnt vmcnt(0)" ::: "memory");
    SBAR;
  }

#undef STAGE_A
#undef STAGE_B
#undef LDA
#undef LDB
#undef MFMA_QUAD
#undef SBAR

  const int crow = l4 * 4;
#pragma unroll
  for (int MF = 0; MF < 8; ++MF)
#pragma unroll
    for (int NF = 0; NF < 4; ++NF)
#pragma unroll
      for (int j = 0; j < 4; ++j) {
        const int r = m0 + wr * 128 + MF * 16 + crow + j;
        const int c = n0 + wc * 64 + NF * 16 + l15;
        Y[(size_t)r * NN + c] = acc[MF][NF][j];
      }
}

// ---------------------------------------------------------------- kernel 4
__global__ __launch_bounds__(256) void gather_k(float* __restrict__ Y,
                                                const int* __restrict__ ridx) {
  __shared__ __align__(16) float rowbuf[NN];
  const int tb = blockIdx.x;      // 0..8191
  const int t = tb >> 5;
  float* yrow = Y + (size_t)tb * NN;
  const int tid = threadIdx.x;
#pragma unroll
  for (int i = 0; i < 2; ++i) {
    int u = tid + i * 256;
    ((fx4*)rowbuf)[u] = ((const fx4*)yrow)[u];
  }
  __syncthreads();
  const int* ir = ridx + t * NN;
#pragma unroll
  for (int i = 0; i < 8; ++i) {
    int j = tid + i * 256;
    yrow[j] = rowbuf[ir[j]];
  }
}

// ---------------------------------------------------------------- launcher
extern "C" void kernel_launch(void* const* d_in, const int* in_sizes, int n_in,
                              void* d_out, int out_size, void* d_ws, size_t ws_size,
                              hipStream_t stream) {
  const float* x      = (const float*)d_in[0];
  const float* W_in   = (const float*)d_in[1];
  const float* bias   = (const float*)d_in[2];
  const float* W_bern = (const float*)d_in[3];
  const int*   ridx   = (const int*)d_in[4];
  float* out = (float*)d_out;
  char* ws = (char*)d_ws;

  __hip_bfloat16* Wt = (__hip_bfloat16*)ws;                       // 8,388,608 B
  __hip_bfloat16* Zb = (__hip_bfloat16*)(ws + (size_t)8388608);   // 33,554,432 B

  wt_convert<<<dim3(64, 64), dim3(32, 8), 0, stream>>>(W_bern, Wt);
  in_scan<<<dim3(32, 32), dim3(256), 0, stream>>>(x, W_in, bias, out, Zb);
  bern_gemm<<<dim3(32, 8), dim3(512), 0, stream>>>(Zb, Wt, out + (size_t)2 * TBN);
  gather_k<<<dim3(8192), dim3(256), 0, stream>>>(out + (size_t)2 * TBN, ridx);
}

// Round 12
// 228.375 us; speedup vs baseline: 1.5131x; 1.5052x over previous
//
#include <hip/hip_runtime.h>
#include <hip/hip_bf16.h>
#include <stdint.h>

// RSNN: T=256 steps, B=32, N_IN=256, N=2048.
// out = [3, T, B, N] fp32: zs | vs | z2s  (TBN elements each)
//
// Pipeline (all on `stream`, stream-ordered):
//   1. wt_convert: W_bern fp32 [k][n] -> Wt bf16 [n][k]   (ws +0, 8 MB)
//   2. in_gemm:    I = x @ W_in + b  (fp32) -- R6 scalar-A design (best of
//                  7 tried: 115us). A via readfirstlane s_load broadcast,
//                  B via gll16 single-buffer + contiguous ds_read_b128.
//   3. scan:       per-neuron serial v scan; writes zs, vs (fp32) and Z bf16
//   4. bern_gemm:  Y = Z @ W_bern  -- 256^2 8-phase bf16 MFMA template
//                  + T1 XCD chunk-mapping (n = bid&7): each XCD keeps one
//                  1MB Wt-panel L2-hot instead of thrashing 12MB.
//   5. gather_k:   z2[t,b,j] = Y[t,b,idx[t,j]]  in place (row via LDS)

#define T_STEPS 256
#define BATCH   32
#define NIN     256
#define NN      2048
#define BN_FLAT (BATCH * NN)            // 65536
#define TBN     (T_STEPS * BATCH * NN)  // 16777216
#define MROWS   (T_STEPS * BATCH)       // 8192

typedef __attribute__((ext_vector_type(4))) float fx4;
typedef __attribute__((ext_vector_type(4))) int   ix4;

__device__ __forceinline__ void gll16(const void* g, void* l) {
  typedef __attribute__((address_space(1))) void gvoid_t;
  typedef __attribute__((address_space(3))) void lvoid_t;
  __builtin_amdgcn_global_load_lds((gvoid_t*)(g), (lvoid_t*)(l), 16, 0, 0);
}

__device__ __forceinline__ void mfma16(fx4& d, ix4 a, ix4 b) {
  asm volatile("v_mfma_f32_16x16x32_bf16 %0, %1, %2, %0" : "+v"(d) : "v"(a), "v"(b));
}

// ---------------------------------------------------------------- kernel 1
__global__ __launch_bounds__(256) void wt_convert(const float* __restrict__ W,
                                                  __hip_bfloat16* __restrict__ Wt) {
  __shared__ float tile[32][33];
  const int k0 = blockIdx.y << 5, n0 = blockIdx.x << 5;
  const int tx = threadIdx.x, ty = threadIdx.y;
#pragma unroll
  for (int i = 0; i < 32; i += 8)
    tile[ty + i][tx] = W[(size_t)(k0 + ty + i) * NN + n0 + tx];
  __syncthreads();
#pragma unroll
  for (int i = 0; i < 32; i += 8)
    Wt[(size_t)(n0 + ty + i) * NN + k0 + tx] = __float2bfloat16(tile[tx][ty + i]);
}

// ---------------------------------------------------------------- kernel 2
// fp32 GEMM: I[8192][2048] = X @ Wi + bias.  (R6 design, measured 115us.)
// Block 32 rows x 256 cols, 4 waves; wave w rows m0+8w..+7, lane cols
// n0+lane*4..+3. A wave-uniform -> readfirstlane row base -> s_load
// (SMEM pipe). B staged [16][256] via gll16, read as ONE contiguous
// conflict-free ds_read_b128 per kk. Grid 2048 blocks = 8 blocks/CU.
__global__ __launch_bounds__(256) void in_gemm(const float* __restrict__ X,
                                               const float* __restrict__ Wi,
                                               const float* __restrict__ bias,
                                               float* __restrict__ I) {
  __shared__ __align__(16) float Bs[16 * 256];  // [k][n] 16 KB
  const int tid = threadIdx.x;
  const int lane = tid & 63;
  const int w = tid >> 6;
  const int m0 = blockIdx.x * 32, n0 = blockIdx.y * 256;
  const int wrow = __builtin_amdgcn_readfirstlane(m0 + 8 * w);
  const float* aP = X + (size_t)wrow * NIN;   // SGPR base -> scalar loads

  fx4 acc[8] = {};

  // B staging: unit u = tid + j*256: row = (u>>6), col16 = (u&63)
  const float* gB = Wi + (size_t)(tid >> 6) * NN + n0 + (tid & 63) * 4;
  char* lB = (char*)Bs + tid * 16;

  for (int k0 = 0; k0 < NIN; k0 += 16) {
#pragma unroll
    for (int j = 0; j < 4; ++j)
      gll16(gB + (size_t)(4 * j) * NN, lB + 4096 * j);
    gB += (size_t)16 * NN;
    __syncthreads();  // drains vmcnt; hidden by 7 other resident blocks
#pragma unroll
    for (int kq = 0; kq < 4; ++kq) {
      fx4 ar[8];
#pragma unroll
      for (int r = 0; r < 8; ++r)
        ar[r] = *(const fx4*)&aP[r * NIN + k0 + kq * 4];  // uniform -> s_load
#pragma unroll
      for (int kk = 0; kk < 4; ++kk) {
        fx4 b = *(const fx4*)&Bs[(kq * 4 + kk) * 256 + lane * 4];
#pragma unroll
        for (int r = 0; r < 8; ++r)
#pragma unroll
          for (int c = 0; c < 4; ++c)
            acc[r][c] = fmaf(ar[r][kk], b[c], acc[r][c]);
      }
    }
    __syncthreads();
  }

#pragma unroll
  for (int r = 0; r < 8; ++r) {
    fx4 res;
#pragma unroll
    for (int c = 0; c < 4; ++c) res[c] = acc[r][c] + bias[n0 + lane * 4 + c];
    *(fx4*)&I[(size_t)(wrow + r) * NN + n0 + lane * 4] = res;
  }
}

// ---------------------------------------------------------------- kernel 3
__device__ __forceinline__ void scan_body(float* zs, float* vsout,
                                          const float* I, __hip_bfloat16* Zb) {
  const int nid = blockIdx.x * 256 + threadIdx.x;  // 0..65535
  float v = 0.f;
  for (int t0 = 0; t0 < T_STEPS; t0 += 8) {
    float iin[8];
#pragma unroll
    for (int u = 0; u < 8; ++u)
      iin[u] = I[(size_t)(t0 + u) * BN_FLAT + nid];
#pragma unroll
    for (int u = 0; u < 8; ++u) {
      float nv = __fadd_rn(__fmul_rn(0.9048374180359595f, v), iin[u]);
      nv = fminf(fmaxf(nv, -1.0f), 1.01f);
      const bool sp = nv > 1.0f;
      const float z = sp ? 1.0f : 0.0f;
      nv = sp ? -1.0f : nv;
      const size_t off = (size_t)(t0 + u) * BN_FLAT + nid;
      zs[off] = z;
      vsout[off] = nv;
      Zb[off] = __float2bfloat16(z);
      v = nv;
    }
  }
}

__global__ __launch_bounds__(256) void scan_sep(float* __restrict__ out,
                                                const float* __restrict__ I,
                                                __hip_bfloat16* __restrict__ Zb) {
  scan_body(out, out + (size_t)TBN, I, Zb);
}

__global__ __launch_bounds__(256) void scan_inp(float* out, __hip_bfloat16* Zb) {
  scan_body(out, out + (size_t)TBN, out + (size_t)TBN, Zb);
}

// ---------------------------------------------------------------- kernel 4
// 256x256 8-phase bf16 MFMA GEMM: Y[8192][2048] = Z[8192][2048] @ Wt^T.
// (R5 schedule) + T1 XCD chunk-map: 1D grid of 256 blocks, n-tile = bid&7,
// m-tile = bid>>3. XCD i (ids == i mod 8) then holds ONE Wt n-panel (1MB,
// L2-hot, x32 reuse) instead of 4 A + 8 B panels (12MB thrash).
__global__ __launch_bounds__(512, 2) void bern_gemm(const __hip_bfloat16* __restrict__ Z,
                                                    const __hip_bfloat16* __restrict__ Wt,
                                                    float* __restrict__ Y) {
  __shared__ __align__(16) char lds[131072];
  const int tid = threadIdx.x;
  const int l = tid & 63, wid = tid >> 6;
  const int wr = wid >> 2, wc = wid & 3;       // 2 x 4 wave grid
  const int l15 = l & 15, l4 = l >> 4;
  const int swz = (l & 7) << 4;                // lane-constant row-XOR
  const int colp[2] = { (l4 * 16) ^ swz, (64 + l4 * 16) ^ swz };
  const int bid = blockIdx.x;                  // 0..255
  const int m0 = (bid >> 3) * 256, n0 = (bid & 7) * 256;
  const int aoff = wr * 16384 + l15 * 128;                          // A: half=wr
  const int boff = 65536 + (wc >> 1) * 16384 + ((wc & 1) * 64 + l15) * 128;
  const int colsel = ((tid & 7) ^ ((tid >> 3) & 7)) * 16;
  const char* gA_ = (const char*)Z + ((size_t)(m0 + (tid >> 3)) << 12) + colsel;
  const char* gB_ = (const char*)Wt + ((size_t)(n0 + (tid >> 3)) << 12) + colsel;

  fx4 acc[8][4] = {};
  ix4 af[4][2], bf[4][2];

#define STAGE_A(tt, h)                                                       \
  do {                                                                       \
    const char* g = gA_ + ((size_t)((h) * 128) << 12) + (size_t)(tt) * 128;  \
    char* d = lds + (((tt) & 1) * 32768) + (h) * 16384 + tid * 16;           \
    gll16(g, d);                                                             \
    gll16(g + ((size_t)64 << 12), d + 8192);                                 \
  } while (0)
#define STAGE_B(tt, h)                                                       \
  do {                                                                       \
    const char* g = gB_ + ((size_t)((h) * 128) << 12) + (size_t)(tt) * 128;  \
    char* d = lds + 65536 + (((tt) & 1) * 32768) + (h) * 16384 + tid * 16;   \
    gll16(g, d);                                                             \
    gll16(g + ((size_t)64 << 12), d + 8192);                                 \
  } while (0)
#define LDA(mh)                                                              \
  _Pragma("unroll") for (int mf = 0; mf < 4; ++mf)                           \
    _Pragma("unroll") for (int ks = 0; ks < 2; ++ks)                         \
      af[mf][ks] = *(const ix4*)(lb + aoff + ((mh)*4 + mf) * 2048 + colp[ks]);
#define LDB(nh)                                                              \
  _Pragma("unroll") for (int nf = 0; nf < 2; ++nf)                           \
    _Pragma("unroll") for (int ks = 0; ks < 2; ++ks)                         \
      bf[(nh)*2 + nf][ks] = *(const ix4*)(lb + boff + ((nh)*2 + nf) * 2048 + colp[ks]);
#define MFMA_QUAD(mh, nh)                                                    \
  do {                                                                       \
    __builtin_amdgcn_s_setprio(1);                                           \
    _Pragma("unroll") for (int ks = 0; ks < 2; ++ks)                         \
      _Pragma("unroll") for (int mf = 0; mf < 4; ++mf)                       \
        _Pragma("unroll") for (int nf = 0; nf < 2; ++nf)                     \
          mfma16(acc[(mh)*4 + mf][(nh)*2 + nf], af[mf][ks], bf[(nh)*2 + nf][ks]); \
    __builtin_amdgcn_s_setprio(0);                                           \
  } while (0)
#define SBAR asm volatile("s_barrier" ::: "memory")

  STAGE_A(0, 0); STAGE_A(0, 1); STAGE_B(0, 0); STAGE_B(0, 1);
  STAGE_B(1, 0); STAGE_B(1, 1);
  asm volatile("s_waitcnt vmcnt(4)" ::: "memory");
  SBAR;

  for (int t = 0; t < 32; ++t) {
    const char* lb = lds + (t & 1) * 32768;
    LDA(0); LDB(0);
    if (t < 31) STAGE_A(t + 1, 0);
    SBAR;
    asm volatile("s_waitcnt lgkmcnt(0)" ::: "memory");
    MFMA_QUAD(0, 0);
    SBAR;
    LDB(1);
    if (t < 31) STAGE_A(t + 1, 1);
    SBAR;
    asm volatile("s_waitcnt lgkmcnt(0)" ::: "memory");
    MFMA_QUAD(0, 1);
    SBAR;
    LDA(1);
    if (t < 30) STAGE_B(t + 2, 0);
    SBAR;
    asm volatile("s_waitcnt lgkmcnt(0)" ::: "memory");
    MFMA_QUAD(1, 0);
    SBAR;
    if (t < 30) STAGE_B(t + 2, 1);
    SBAR;
    MFMA_QUAD(1, 1);
    if (t < 30) asm volatile("s_waitcnt vmcnt(4)" ::: "memory");
    else        asm volatile("s_waitcnt vmcnt(0)" ::: "memory");
    SBAR;
  }

#undef STAGE_A
#undef STAGE_B
#undef LDA
#undef LDB
#undef MFMA_QUAD
#undef SBAR

  const int crow = l4 * 4;
#pragma unroll
  for (int MF = 0; MF < 8; ++MF)
#pragma unroll
    for (int NF = 0; NF < 4; ++NF)
#pragma unroll
      for (int j = 0; j < 4; ++j) {
        const int r = m0 + wr * 128 + MF * 16 + crow + j;
        const int c = n0 + wc * 64 + NF * 16 + l15;
        Y[(size_t)r * NN + c] = acc[MF][NF][j];
      }
}

// ---------------------------------------------------------------- kernel 5
__global__ __launch_bounds__(256) void gather_k(float* __restrict__ Y,
                                                const int* __restrict__ ridx) {
  __shared__ __align__(16) float rowbuf[NN];
  const int tb = blockIdx.x;      // 0..8191
  const int t = tb >> 5;
  float* yrow = Y + (size_t)tb * NN;
  const int tid = threadIdx.x;
#pragma unroll
  for (int i = 0; i < 2; ++i) {
    int u = tid + i * 256;
    ((fx4*)rowbuf)[u] = ((const fx4*)yrow)[u];
  }
  __syncthreads();
  const int* ir = ridx + t * NN;
#pragma unroll
  for (int i = 0; i < 8; ++i) {
    int j = tid + i * 256;
    yrow[j] = rowbuf[ir[j]];
  }
}

// ---------------------------------------------------------------- launcher
extern "C" void kernel_launch(void* const* d_in, const int* in_sizes, int n_in,
                              void* d_out, int out_size, void* d_ws, size_t ws_size,
                              hipStream_t stream) {
  const float* x      = (const float*)d_in[0];
  const float* W_in   = (const float*)d_in[1];
  const float* bias   = (const float*)d_in[2];
  const float* W_bern = (const float*)d_in[3];
  const int*   ridx   = (const int*)d_in[4];
  float* out = (float*)d_out;
  char* ws = (char*)d_ws;

  __hip_bfloat16* Wt = (__hip_bfloat16*)ws;                       // 8,388,608 B
  __hip_bfloat16* Zb = (__hip_bfloat16*)(ws + (size_t)8388608);   // 33,554,432 B
  const size_t offI = 41943040;                                   // I: 67,108,864 B
  const bool sep = ws_size >= (size_t)109051904;
  float* Ibuf = sep ? (float*)(ws + offI) : (out + (size_t)TBN);

  wt_convert<<<dim3(64, 64), dim3(32, 8), 0, stream>>>(W_bern, Wt);
  in_gemm<<<dim3(256, 8), dim3(256), 0, stream>>>(x, W_in, bias, Ibuf);
  if (sep)
    scan_sep<<<dim3(256), dim3(256), 0, stream>>>(out, Ibuf, Zb);
  else
    scan_inp<<<dim3(256), dim3(256), 0, stream>>>(out, Zb);
  bern_gemm<<<dim3(256), dim3(512), 0, stream>>>(Zb, Wt, out + (size_t)2 * TBN);
  gather_k<<<dim3(8192), dim3(256), 0, stream>>>(out + (size_t)2 * TBN, ridx);
}